// Round 7
// baseline (15.939 us; speedup 1.0000x reference)
//
#include <hip/hip_runtime.h>
#include <math.h>

#define NTAB 256             // table intervals; table has NTAB+1 = 257 entries
#define TLIM 8.0f            // t range [-TLIM, TLIM]

// fast tanh / sigmoid via v_exp_f32 + v_rcp_f32 (rel err ~1e-5, threshold 1.5e-2)
__device__ __forceinline__ float ftanh(float x) {
    float e = __expf(2.0f * x);
    return 1.0f - 2.0f * __builtin_amdgcn_rcpf(e + 1.0f);
}
__device__ __forceinline__ float fsigmoid(float x) {
    return __builtin_amdgcn_rcpf(1.0f + __expf(-x));
}

// ---------------------------------------------------------------------------
// Kernel 1: build LUT p(t), 257 entries. 256-thread blocks (4 waves), one
// entry per wave, 65 blocks. e1_w staged ROW-MAJOR in LDS with chunk-XOR
// swizzle so lane j reads its own row as 32x ds_read_b128 conflict-free:
//   slot(row, chunk) = (row*32 + (row&31)) ^ chunk      (float4 index)
// Read: lane j, iter c -> lwt4[bidx ^ c], bidx = j*32 + (j&31).
// This replaces 128 ds_read_b32/wave (round 6, ~740cyc) with 32 b128 (~400).
// ---------------------------------------------------------------------------
__global__ __launch_bounds__(256) void build_tab_kernel(
    const float* __restrict__ e0w, const float* __restrict__ e0b,
    const float* __restrict__ e1w, const float* __restrict__ e1b,
    const float* __restrict__ e2w, const float* __restrict__ e2b,
    const float* __restrict__ fmw, const float* __restrict__ fmb,
    const float* __restrict__ c1w, const float* __restrict__ c1b,
    const float* __restrict__ p1w, const float* __restrict__ p1b,
    const float* __restrict__ c2w, const float* __restrict__ c2b,
    const float* __restrict__ p2w, const float* __restrict__ p2b,
    const float* __restrict__ c3w, const float* __restrict__ c3b,
    const float* __restrict__ hw,  const float* __restrict__ hb,
    float* __restrict__ tab)
{
    __shared__ float4 lwt4[2048];          // 32 KB, swizzled row-major e1w
    const int tid = threadIdx.x;

    // Stage: 2048 float4, 8 per thread, coalesced loads, swizzled LDS writes.
    const float4* e1w4 = (const float4*)e1w;
    #pragma unroll
    for (int i = 0; i < 8; ++i) {
        int idx4 = i * 256 + tid;          // 0..2047
        int row  = idx4 >> 5;              // 0..63
        int ch   = idx4 & 31;              // 0..31
        float4 v = e1w4[idx4];
        lwt4[(row * 32 + (row & 31)) ^ ch] = v;
    }
    __syncthreads();

    const int wave = tid >> 6;
    const int lane = tid & 63;
    const int e    = blockIdx.x * 4 + wave;       // 0..259
    const int ec   = (e <= NTAB) ? e : NTAB;      // clamp: uniform math

    const float t  = -TLIM + (2.0f * TLIM) * (float)ec / (float)NTAB;
    const float sv = fsigmoid(t);

    // h2[lane] = relu( sum_k e1w[lane,k] * relu(e0w[k]*sv + e0b[k]) + e1b[lane] )
    const int bidx = lane * 32 + (lane & 31);
    float a0 = e1b[lane], a1 = 0.0f, a2 = 0.0f, a3 = 0.0f;
    #pragma unroll
    for (int c = 0; c < 32; ++c) {
        float4 w4 = lwt4[bidx ^ c];        // chunk c of row `lane`
        const int k = 4 * c;
        float h10 = fmaxf(fmaf(e0w[k + 0], sv, e0b[k + 0]), 0.0f);
        float h11 = fmaxf(fmaf(e0w[k + 1], sv, e0b[k + 1]), 0.0f);
        float h12 = fmaxf(fmaf(e0w[k + 2], sv, e0b[k + 2]), 0.0f);
        float h13 = fmaxf(fmaf(e0w[k + 3], sv, e0b[k + 3]), 0.0f);
        a0 = fmaf(w4.x, h10, a0);
        a1 = fmaf(w4.y, h11, a1);
        a2 = fmaf(w4.z, h12, a2);
        a3 = fmaf(w4.w, h13, a3);
    }
    float h2 = fmaxf((a0 + a1) + (a2 + a3), 0.0f);

    // latent = e2_w (2x64) @ h2 + e2_b : butterfly reduction
    float v0 = e2w[lane] * h2;
    float v1 = e2w[64 + lane] * h2;
    #pragma unroll
    for (int off = 32; off > 0; off >>= 1) {
        v0 += __shfl_xor(v0, off);
        v1 += __shfl_xor(v1, off);
    }
    float l0 = v0 + e2b[0];
    float l1 = v1 + e2b[1];

    // QCNN tanh chain (tiny; redundant per lane; fast-exp tanh)
    float y0[4], y1[4], y2[3], y3[2];
    #pragma unroll
    for (int o = 0; o < 4; ++o)
        y0[o] = ftanh(fmaf(fmw[o*2], l0, fmaf(fmw[o*2+1], l1, fmb[o])));
    #pragma unroll
    for (int o = 0; o < 4; ++o)
        y1[o] = ftanh(fmaf(c1w[o*4], y0[0], fmaf(c1w[o*4+1], y0[1],
                      fmaf(c1w[o*4+2], y0[2], fmaf(c1w[o*4+3], y0[3], c1b[o])))));
    #pragma unroll
    for (int o = 0; o < 3; ++o)
        y2[o] = ftanh(fmaf(p1w[o*4], y1[0], fmaf(p1w[o*4+1], y1[1],
                      fmaf(p1w[o*4+2], y1[2], fmaf(p1w[o*4+3], y1[3], p1b[o])))));
    #pragma unroll
    for (int o = 0; o < 2; ++o)
        y3[o] = ftanh(fmaf(c2w[o*3], y2[0], fmaf(c2w[o*3+1], y2[1],
                      fmaf(c2w[o*3+2], y2[2], c2b[o]))));
    float y4 = ftanh(fmaf(p2w[0], y3[0], fmaf(p2w[1], y3[1], p2b[0])));
    float y5 = ftanh(fmaf(c3w[0], y4, c3b[0]));
    float g0 = fmaf(hw[0], y5, hb[0]);
    float g1 = fmaf(hw[1], y5, hb[1]);
    float p0 = fsigmoid(g0 - g1);          // softmax over 2 logits

    if (lane == 0 && e <= NTAB) tab[e] = p0;
}

// ---------------------------------------------------------------------------
// Kernel 2: memory-bound eval, 8 samples/thread, 512 blocks (unchanged from
// round 6: lane-dense dwordx4 loads / b64 stores, 256-entry LDS lerp table).
// ---------------------------------------------------------------------------
__global__ __launch_bounds__(256) void eval_kernel(
    const float4* __restrict__ x4,
    const float*  __restrict__ convw,
    const float*  __restrict__ convb,
    const float*  __restrict__ tab,
    float2* __restrict__ out2)
{
    __shared__ float2 ltab[NTAB];
    const int tid  = threadIdx.x;
    const int base = blockIdx.x * 2048;   // 2048 samples per block

    // Issue x loads first: 8 dwordx4 in flight per lane during staging.
    float4 xs[8];
    #pragma unroll
    for (int j = 0; j < 8; ++j)
        xs[j] = x4[base + j * 256 + tid];

    // Stage table: one (value, delta) entry per thread.
    {
        float v  = tab[tid];
        float vn = tab[tid + 1];
        ltab[tid] = make_float2(v, vn - v);
    }
    __syncthreads();

    const float scale = (float)NTAB / (2.0f * TLIM);   // 16.0f
    const float w0 = convw[0] * scale, w1 = convw[1] * scale,
                w2 = convw[2] * scale, w3 = convw[3] * scale;
    const float cb = (convb[0] + TLIM) * scale;

    #pragma unroll
    for (int j = 0; j < 8; ++j) {
        float f = fmaf(xs[j].x, w0, fmaf(xs[j].y, w1,
                  fmaf(xs[j].z, w2, fmaf(xs[j].w, w3, cb))));
        f = fminf(fmaxf(f, 0.0f), (float)NTAB - 0.001f);
        int   k = (int)f;
        float r = f - (float)k;
        float2 vd = ltab[k];
        float p = fmaf(r, vd.y, vd.x);
        out2[base + j * 256 + tid] = make_float2(p, 1.0f - p);
    }
}

extern "C" void kernel_launch(void* const* d_in, const int* in_sizes, int n_in,
                              void* d_out, int out_size, void* d_ws, size_t ws_size,
                              hipStream_t stream) {
    const float* x     = (const float*)d_in[0];
    const float* convw = (const float*)d_in[1];
    const float* convb = (const float*)d_in[2];
    const float* e0w   = (const float*)d_in[3];
    const float* e0b   = (const float*)d_in[4];
    const float* e1w   = (const float*)d_in[5];
    const float* e1b   = (const float*)d_in[6];
    const float* e2w   = (const float*)d_in[7];
    const float* e2b   = (const float*)d_in[8];
    const float* fmw   = (const float*)d_in[9];
    const float* fmb   = (const float*)d_in[10];
    const float* c1w   = (const float*)d_in[11];
    const float* c1b   = (const float*)d_in[12];
    const float* p1w   = (const float*)d_in[13];
    const float* p1b   = (const float*)d_in[14];
    const float* c2w   = (const float*)d_in[15];
    const float* c2b   = (const float*)d_in[16];
    const float* p2w   = (const float*)d_in[17];
    const float* p2b   = (const float*)d_in[18];
    const float* c3w   = (const float*)d_in[19];
    const float* c3b   = (const float*)d_in[20];
    const float* hw    = (const float*)d_in[21];
    const float* hb    = (const float*)d_in[22];

    float* tab = (float*)d_ws;                 // 257 floats

    const int B = in_sizes[0] / 4;             // 1048576 samples

    // Build LUT: 4 entries per 256-thread block -> 65 blocks cover 257.
    int nblocks_tab = (NTAB + 1 + 3) / 4;      // 65
    build_tab_kernel<<<nblocks_tab, 256, 0, stream>>>(
        e0w, e0b, e1w, e1b, e2w, e2b, fmw, fmb, c1w, c1b,
        p1w, p1b, c2w, c2b, p2w, p2b, c3w, c3b, hw, hb, tab);

    // Evaluate: 2048 samples per block.
    int nblocks = B / 2048;                    // 512
    eval_kernel<<<nblocks, 256, 0, stream>>>(
        (const float4*)x, convw, convb, tab, (float2*)d_out);
}

// Round 8
// 15.131 us; speedup vs baseline: 1.0534x; 1.0534x over previous
//
#include <hip/hip_runtime.h>
#include <math.h>

#define NTAB 128             // table intervals; table has NTAB+1 = 129 entries
#define TLIM 8.0f            // t range [-TLIM, TLIM]

// fast tanh / sigmoid via v_exp_f32 + v_rcp_f32 (rel err ~1e-5, threshold 1.5e-2)
__device__ __forceinline__ float ftanh(float x) {
    float e = __expf(2.0f * x);
    return 1.0f - 2.0f * __builtin_amdgcn_rcpf(e + 1.0f);
}
__device__ __forceinline__ float fsigmoid(float x) {
    return __builtin_amdgcn_rcpf(1.0f + __expf(-x));
}

// ---------------------------------------------------------------------------
// Kernel 1: build LUT p(t), 129 entries. R6-proven structure: 512-thread
// blocks, 8 waves, one entry per wave -> 17 blocks. e1_w (64x128) staged
// transposed in LDS (stride 65, conflict-free), float4 global staging.
// ---------------------------------------------------------------------------
__global__ __launch_bounds__(512) void build_tab_kernel(
    const float* __restrict__ e0w, const float* __restrict__ e0b,
    const float* __restrict__ e1w, const float* __restrict__ e1b,
    const float* __restrict__ e2w, const float* __restrict__ e2b,
    const float* __restrict__ fmw, const float* __restrict__ fmb,
    const float* __restrict__ c1w, const float* __restrict__ c1b,
    const float* __restrict__ p1w, const float* __restrict__ p1b,
    const float* __restrict__ c2w, const float* __restrict__ c2b,
    const float* __restrict__ p2w, const float* __restrict__ p2b,
    const float* __restrict__ c3w, const float* __restrict__ c3b,
    const float* __restrict__ hw,  const float* __restrict__ hb,
    float* __restrict__ tab)
{
    __shared__ float wt[128 * 65];
    const int tid = threadIdx.x;

    // Stage e1_w transposed: 2048 float4 total, 4 per thread.
    const float4* e1w4 = (const float4*)e1w;
    #pragma unroll
    for (int i = 0; i < 4; ++i) {
        int idx4 = i * 512 + tid;         // 0..2047
        float4 v = e1w4[idx4];
        int base = idx4 * 4;
        int j = base >> 7;                // row 0..63
        int k = base & 127;               // col 0..124 (multiple of 4)
        wt[(k + 0) * 65 + j] = v.x;
        wt[(k + 1) * 65 + j] = v.y;
        wt[(k + 2) * 65 + j] = v.z;
        wt[(k + 3) * 65 + j] = v.w;
    }
    __syncthreads();

    const int wave = tid >> 6;
    const int lane = tid & 63;
    const int e    = blockIdx.x * 8 + wave;       // table entry (0..135)
    const int ec   = (e <= NTAB) ? e : NTAB;      // clamp: uniform math

    const float t  = -TLIM + (2.0f * TLIM) * (float)ec / (float)NTAB;
    const float sv = fsigmoid(t);

    // h2[lane] = relu(sum_k e1w[lane,k]*relu(e0w[k]*sv+e0b[k]) + e1b[lane])
    float a0 = e1b[lane], a1 = 0.0f, a2 = 0.0f, a3 = 0.0f;
    #pragma unroll 4
    for (int k = 0; k < 128; k += 4) {
        float h10 = fmaxf(fmaf(e0w[k + 0], sv, e0b[k + 0]), 0.0f);
        float h11 = fmaxf(fmaf(e0w[k + 1], sv, e0b[k + 1]), 0.0f);
        float h12 = fmaxf(fmaf(e0w[k + 2], sv, e0b[k + 2]), 0.0f);
        float h13 = fmaxf(fmaf(e0w[k + 3], sv, e0b[k + 3]), 0.0f);
        a0 = fmaf(wt[(k + 0) * 65 + lane], h10, a0);
        a1 = fmaf(wt[(k + 1) * 65 + lane], h11, a1);
        a2 = fmaf(wt[(k + 2) * 65 + lane], h12, a2);
        a3 = fmaf(wt[(k + 3) * 65 + lane], h13, a3);
    }
    float h2 = fmaxf((a0 + a1) + (a2 + a3), 0.0f);

    // latent = e2_w (2x64) @ h2 + e2_b : butterfly reduction
    float v0 = e2w[lane] * h2;
    float v1 = e2w[64 + lane] * h2;
    #pragma unroll
    for (int off = 32; off > 0; off >>= 1) {
        v0 += __shfl_xor(v0, off);
        v1 += __shfl_xor(v1, off);
    }
    float l0 = v0 + e2b[0];
    float l1 = v1 + e2b[1];

    // QCNN tanh chain (tiny; redundant per lane; fast-exp tanh)
    float y0[4], y1[4], y2[3], y3[2];
    #pragma unroll
    for (int o = 0; o < 4; ++o)
        y0[o] = ftanh(fmaf(fmw[o*2], l0, fmaf(fmw[o*2+1], l1, fmb[o])));
    #pragma unroll
    for (int o = 0; o < 4; ++o)
        y1[o] = ftanh(fmaf(c1w[o*4], y0[0], fmaf(c1w[o*4+1], y0[1],
                      fmaf(c1w[o*4+2], y0[2], fmaf(c1w[o*4+3], y0[3], c1b[o])))));
    #pragma unroll
    for (int o = 0; o < 3; ++o)
        y2[o] = ftanh(fmaf(p1w[o*4], y1[0], fmaf(p1w[o*4+1], y1[1],
                      fmaf(p1w[o*4+2], y1[2], fmaf(p1w[o*4+3], y1[3], p1b[o])))));
    #pragma unroll
    for (int o = 0; o < 2; ++o)
        y3[o] = ftanh(fmaf(c2w[o*3], y2[0], fmaf(c2w[o*3+1], y2[1],
                      fmaf(c2w[o*3+2], y2[2], c2b[o]))));
    float y4 = ftanh(fmaf(p2w[0], y3[0], fmaf(p2w[1], y3[1], p2b[0])));
    float y5 = ftanh(fmaf(c3w[0], y4, c3b[0]));
    float g0 = fmaf(hw[0], y5, hb[0]);
    float g1 = fmaf(hw[1], y5, hb[1]);
    float p0 = fsigmoid(g0 - g1);          // softmax over 2 logits

    if (lane == 0 && e <= NTAB) tab[e] = p0;
}

// ---------------------------------------------------------------------------
// Kernel 2: memory-bound eval, 8 samples/thread, 512 blocks (R6 structure:
// lane-dense dwordx4 loads / b64 stores). LDS table = 128 (value,delta)
// entries staged by threads 0..127 (clamp guarantees k<=127).
// ---------------------------------------------------------------------------
__global__ __launch_bounds__(256) void eval_kernel(
    const float4* __restrict__ x4,
    const float*  __restrict__ convw,
    const float*  __restrict__ convb,
    const float*  __restrict__ tab,
    float2* __restrict__ out2)
{
    __shared__ float2 ltab[NTAB];
    const int tid  = threadIdx.x;
    const int base = blockIdx.x * 2048;   // 2048 samples per block

    // Issue x loads first: 8 dwordx4 in flight per lane during staging.
    float4 xs[8];
    #pragma unroll
    for (int j = 0; j < 8; ++j)
        xs[j] = x4[base + j * 256 + tid];

    // Stage table: one (value, delta) entry per thread for tid < 128.
    if (tid < NTAB) {
        float v  = tab[tid];
        float vn = tab[tid + 1];
        ltab[tid] = make_float2(v, vn - v);
    }
    __syncthreads();

    const float scale = (float)NTAB / (2.0f * TLIM);   // 8.0f
    const float w0 = convw[0] * scale, w1 = convw[1] * scale,
                w2 = convw[2] * scale, w3 = convw[3] * scale;
    const float cb = (convb[0] + TLIM) * scale;

    #pragma unroll
    for (int j = 0; j < 8; ++j) {
        float f = fmaf(xs[j].x, w0, fmaf(xs[j].y, w1,
                  fmaf(xs[j].z, w2, fmaf(xs[j].w, w3, cb))));
        f = fminf(fmaxf(f, 0.0f), (float)NTAB - 0.001f);
        int   k = (int)f;
        float r = f - (float)k;
        float2 vd = ltab[k];
        float p = fmaf(r, vd.y, vd.x);
        out2[base + j * 256 + tid] = make_float2(p, 1.0f - p);
    }
}

extern "C" void kernel_launch(void* const* d_in, const int* in_sizes, int n_in,
                              void* d_out, int out_size, void* d_ws, size_t ws_size,
                              hipStream_t stream) {
    const float* x     = (const float*)d_in[0];
    const float* convw = (const float*)d_in[1];
    const float* convb = (const float*)d_in[2];
    const float* e0w   = (const float*)d_in[3];
    const float* e0b   = (const float*)d_in[4];
    const float* e1w   = (const float*)d_in[5];
    const float* e1b   = (const float*)d_in[6];
    const float* e2w   = (const float*)d_in[7];
    const float* e2b   = (const float*)d_in[8];
    const float* fmw   = (const float*)d_in[9];
    const float* fmb   = (const float*)d_in[10];
    const float* c1w   = (const float*)d_in[11];
    const float* c1b   = (const float*)d_in[12];
    const float* p1w   = (const float*)d_in[13];
    const float* p1b   = (const float*)d_in[14];
    const float* c2w   = (const float*)d_in[15];
    const float* c2b   = (const float*)d_in[16];
    const float* p2w   = (const float*)d_in[17];
    const float* p2b   = (const float*)d_in[18];
    const float* c3w   = (const float*)d_in[19];
    const float* c3b   = (const float*)d_in[20];
    const float* hw    = (const float*)d_in[21];
    const float* hb    = (const float*)d_in[22];

    float* tab = (float*)d_ws;                 // 129 floats

    const int B = in_sizes[0] / 4;             // 1048576 samples

    // Build LUT: 8 entries per 512-thread block -> 17 blocks cover 129.
    int nblocks_tab = (NTAB + 1 + 7) / 8;      // 17
    build_tab_kernel<<<nblocks_tab, 512, 0, stream>>>(
        e0w, e0b, e1w, e1b, e2w, e2b, fmw, fmb, c1w, c1b,
        p1w, p1b, c2w, c2b, p2w, p2b, c3w, c3b, hw, hb, tab);

    // Evaluate: 2048 samples per block.
    int nblocks = B / 2048;                    // 512
    eval_kernel<<<nblocks, 256, 0, stream>>>(
        (const float4*)x, convw, convb, tab, (float2*)d_out);
}

// Round 9
// 13.936 us; speedup vs baseline: 1.1437x; 1.0857x over previous
//
#include <hip/hip_runtime.h>
#include <math.h>

#define NTAB 128             // table intervals; table has NTAB+1 = 129 entries
#define TLIM 8.0f            // t range [-TLIM, TLIM]

// fast tanh / sigmoid via v_exp_f32 + v_rcp_f32 (rel err ~1e-5, threshold 1.5e-2)
__device__ __forceinline__ float ftanh(float x) {
    float e = __expf(2.0f * x);
    return 1.0f - 2.0f * __builtin_amdgcn_rcpf(e + 1.0f);
}
__device__ __forceinline__ float fsigmoid(float x) {
    return __builtin_amdgcn_rcpf(1.0f + __expf(-x));
}

// ---------------------------------------------------------------------------
// Kernel 1: build LUT p(t), 129 entries. ONE WAVE per block, one entry per
// block, 129 blocks -> zero inter-wave LDS contention (R8 had 8 waves
// sharing one CU's LDS pipe: 1024 ds_read_b32 ~ 2.5us serialized).
// e1_w (64x128) staged as swizzled float4 rows:
//   slot(row, ch) = (row*32 + (row&31)) ^ ch   (float4 index, bijective
//   within each row's 32-slot span; even bank spread on write & read).
// Lane j reads its row as 32 x ds_read_b128: lwt4[(j*32+(j&31)) ^ c].
// Total LDS per block: 32 write_b128 + 32 read_b128 ~ 0.3us.
// ---------------------------------------------------------------------------
__global__ __launch_bounds__(64) void build_tab_kernel(
    const float* __restrict__ e0w, const float* __restrict__ e0b,
    const float* __restrict__ e1w, const float* __restrict__ e1b,
    const float* __restrict__ e2w, const float* __restrict__ e2b,
    const float* __restrict__ fmw, const float* __restrict__ fmb,
    const float* __restrict__ c1w, const float* __restrict__ c1b,
    const float* __restrict__ p1w, const float* __restrict__ p1b,
    const float* __restrict__ c2w, const float* __restrict__ c2b,
    const float* __restrict__ p2w, const float* __restrict__ p2b,
    const float* __restrict__ c3w, const float* __restrict__ c3b,
    const float* __restrict__ hw,  const float* __restrict__ hb,
    float* __restrict__ tab)
{
    __shared__ float4 lwt4[2048];          // 32 KB, swizzled row-major e1w
    const int lane = threadIdx.x;          // 0..63 (one wave)

    // Stage: 2048 float4, 32 per lane, coalesced global, swizzled b128 writes.
    const float4* e1w4 = (const float4*)e1w;
    #pragma unroll
    for (int i = 0; i < 32; ++i) {
        int idx4 = i * 64 + lane;          // 0..2047
        int row  = idx4 >> 5;              // 0..63
        int ch   = idx4 & 31;              // 0..31
        lwt4[(row * 32 + (row & 31)) ^ ch] = e1w4[idx4];
    }
    __syncthreads();                       // single wave: just a waitcnt

    const int e = blockIdx.x;              // table entry 0..NTAB

    const float t  = -TLIM + (2.0f * TLIM) * (float)e / (float)NTAB;
    const float sv = fsigmoid(t);

    // h2[lane] = relu( sum_k e1w[lane,k] * relu(e0w[k]*sv + e0b[k]) + e1b[lane] )
    const int bidx = lane * 32 + (lane & 31);
    float a0 = e1b[lane], a1 = 0.0f, a2 = 0.0f, a3 = 0.0f;
    #pragma unroll
    for (int c = 0; c < 32; ++c) {
        float4 w4 = lwt4[bidx ^ c];        // chunk c of row `lane`
        const int k = 4 * c;
        float h10 = fmaxf(fmaf(e0w[k + 0], sv, e0b[k + 0]), 0.0f);
        float h11 = fmaxf(fmaf(e0w[k + 1], sv, e0b[k + 1]), 0.0f);
        float h12 = fmaxf(fmaf(e0w[k + 2], sv, e0b[k + 2]), 0.0f);
        float h13 = fmaxf(fmaf(e0w[k + 3], sv, e0b[k + 3]), 0.0f);
        a0 = fmaf(w4.x, h10, a0);
        a1 = fmaf(w4.y, h11, a1);
        a2 = fmaf(w4.z, h12, a2);
        a3 = fmaf(w4.w, h13, a3);
    }
    float h2 = fmaxf((a0 + a1) + (a2 + a3), 0.0f);

    // latent = e2_w (2x64) @ h2 + e2_b : butterfly reduction
    float v0 = e2w[lane] * h2;
    float v1 = e2w[64 + lane] * h2;
    #pragma unroll
    for (int off = 32; off > 0; off >>= 1) {
        v0 += __shfl_xor(v0, off);
        v1 += __shfl_xor(v1, off);
    }
    float l0 = v0 + e2b[0];
    float l1 = v1 + e2b[1];

    // QCNN tanh chain (tiny; redundant per lane; fast-exp tanh)
    float y0[4], y1[4], y2[3], y3[2];
    #pragma unroll
    for (int o = 0; o < 4; ++o)
        y0[o] = ftanh(fmaf(fmw[o*2], l0, fmaf(fmw[o*2+1], l1, fmb[o])));
    #pragma unroll
    for (int o = 0; o < 4; ++o)
        y1[o] = ftanh(fmaf(c1w[o*4], y0[0], fmaf(c1w[o*4+1], y0[1],
                      fmaf(c1w[o*4+2], y0[2], fmaf(c1w[o*4+3], y0[3], c1b[o])))));
    #pragma unroll
    for (int o = 0; o < 3; ++o)
        y2[o] = ftanh(fmaf(p1w[o*4], y1[0], fmaf(p1w[o*4+1], y1[1],
                      fmaf(p1w[o*4+2], y1[2], fmaf(p1w[o*4+3], y1[3], p1b[o])))));
    #pragma unroll
    for (int o = 0; o < 2; ++o)
        y3[o] = ftanh(fmaf(c2w[o*3], y2[0], fmaf(c2w[o*3+1], y2[1],
                      fmaf(c2w[o*3+2], y2[2], c2b[o]))));
    float y4 = ftanh(fmaf(p2w[0], y3[0], fmaf(p2w[1], y3[1], p2b[0])));
    float y5 = ftanh(fmaf(c3w[0], y4, c3b[0]));
    float g0 = fmaf(hw[0], y5, hb[0]);
    float g1 = fmaf(hw[1], y5, hb[1]);
    float p0 = fsigmoid(g0 - g1);          // softmax over 2 logits

    if (lane == 0) tab[e] = p0;
}

// ---------------------------------------------------------------------------
// Kernel 2: memory-bound eval, 8 samples/thread, 512 blocks (R6/R8 structure:
// lane-dense dwordx4 loads / b64 stores). LDS table = 128 (value,delta)
// entries staged by threads 0..127 (clamp guarantees k<=127).
// ---------------------------------------------------------------------------
__global__ __launch_bounds__(256) void eval_kernel(
    const float4* __restrict__ x4,
    const float*  __restrict__ convw,
    const float*  __restrict__ convb,
    const float*  __restrict__ tab,
    float2* __restrict__ out2)
{
    __shared__ float2 ltab[NTAB];
    const int tid  = threadIdx.x;
    const int base = blockIdx.x * 2048;   // 2048 samples per block

    // Issue x loads first: 8 dwordx4 in flight per lane during staging.
    float4 xs[8];
    #pragma unroll
    for (int j = 0; j < 8; ++j)
        xs[j] = x4[base + j * 256 + tid];

    // Stage table: one (value, delta) entry per thread for tid < 128.
    if (tid < NTAB) {
        float v  = tab[tid];
        float vn = tab[tid + 1];
        ltab[tid] = make_float2(v, vn - v);
    }
    __syncthreads();

    const float scale = (float)NTAB / (2.0f * TLIM);   // 8.0f
    const float w0 = convw[0] * scale, w1 = convw[1] * scale,
                w2 = convw[2] * scale, w3 = convw[3] * scale;
    const float cb = (convb[0] + TLIM) * scale;

    #pragma unroll
    for (int j = 0; j < 8; ++j) {
        float f = fmaf(xs[j].x, w0, fmaf(xs[j].y, w1,
                  fmaf(xs[j].z, w2, fmaf(xs[j].w, w3, cb))));
        f = fminf(fmaxf(f, 0.0f), (float)NTAB - 0.001f);
        int   k = (int)f;
        float r = f - (float)k;
        float2 vd = ltab[k];
        float p = fmaf(r, vd.y, vd.x);
        out2[base + j * 256 + tid] = make_float2(p, 1.0f - p);
    }
}

extern "C" void kernel_launch(void* const* d_in, const int* in_sizes, int n_in,
                              void* d_out, int out_size, void* d_ws, size_t ws_size,
                              hipStream_t stream) {
    const float* x     = (const float*)d_in[0];
    const float* convw = (const float*)d_in[1];
    const float* convb = (const float*)d_in[2];
    const float* e0w   = (const float*)d_in[3];
    const float* e0b   = (const float*)d_in[4];
    const float* e1w   = (const float*)d_in[5];
    const float* e1b   = (const float*)d_in[6];
    const float* e2w   = (const float*)d_in[7];
    const float* e2b   = (const float*)d_in[8];
    const float* fmw   = (const float*)d_in[9];
    const float* fmb   = (const float*)d_in[10];
    const float* c1w   = (const float*)d_in[11];
    const float* c1b   = (const float*)d_in[12];
    const float* p1w   = (const float*)d_in[13];
    const float* p1b   = (const float*)d_in[14];
    const float* c2w   = (const float*)d_in[15];
    const float* c2b   = (const float*)d_in[16];
    const float* p2w   = (const float*)d_in[17];
    const float* p2b   = (const float*)d_in[18];
    const float* c3w   = (const float*)d_in[19];
    const float* c3b   = (const float*)d_in[20];
    const float* hw    = (const float*)d_in[21];
    const float* hb    = (const float*)d_in[22];

    float* tab = (float*)d_ws;                 // 129 floats

    const int B = in_sizes[0] / 4;             // 1048576 samples

    // Build LUT: one wave / one entry per block, 129 blocks (all parallel).
    build_tab_kernel<<<NTAB + 1, 64, 0, stream>>>(
        e0w, e0b, e1w, e1b, e2w, e2b, fmw, fmb, c1w, c1b,
        p1w, p1b, c2w, c2b, p2w, p2b, c3w, c3b, hw, hb, tab);

    // Evaluate: 2048 samples per block.
    int nblocks = B / 2048;                    // 512
    eval_kernel<<<nblocks, 256, 0, stream>>>(
        (const float4*)x, convw, convb, tab, (float2*)d_out);
}

// Round 11
// 13.880 us; speedup vs baseline: 1.1483x; 1.0040x over previous
//
#include <hip/hip_runtime.h>
#include <math.h>

#define NTAB 128             // table intervals; table has NTAB+1 = 129 entries
#define TLIM 8.0f            // t range [-TLIM, TLIM]

// clang native vector types (ext_vector_type) — required for
// __builtin_nontemporal_load/store, which rejects HIP_vector_type structs.
typedef float vf4 __attribute__((ext_vector_type(4)));
typedef float vf2 __attribute__((ext_vector_type(2)));

// fast tanh / sigmoid via v_exp_f32 + v_rcp_f32 (rel err ~1e-5, threshold 1.5e-2)
__device__ __forceinline__ float ftanh(float x) {
    float e = __expf(2.0f * x);
    return 1.0f - 2.0f * __builtin_amdgcn_rcpf(e + 1.0f);
}
__device__ __forceinline__ float fsigmoid(float x) {
    return __builtin_amdgcn_rcpf(1.0f + __expf(-x));
}

// ---------------------------------------------------------------------------
// Kernel 1 (R9-proven, unchanged): build LUT p(t), 129 entries. ONE WAVE per
// block, one entry per block, 129 parallel blocks. e1_w staged as swizzled
// float4 rows: slot(row,ch) = (row*32+(row&31))^ch; lane j reads its row as
// 32x ds_read_b128 conflict-minimal.
// ---------------------------------------------------------------------------
__global__ __launch_bounds__(64) void build_tab_kernel(
    const float* __restrict__ e0w, const float* __restrict__ e0b,
    const float* __restrict__ e1w, const float* __restrict__ e1b,
    const float* __restrict__ e2w, const float* __restrict__ e2b,
    const float* __restrict__ fmw, const float* __restrict__ fmb,
    const float* __restrict__ c1w, const float* __restrict__ c1b,
    const float* __restrict__ p1w, const float* __restrict__ p1b,
    const float* __restrict__ c2w, const float* __restrict__ c2b,
    const float* __restrict__ p2w, const float* __restrict__ p2b,
    const float* __restrict__ c3w, const float* __restrict__ c3b,
    const float* __restrict__ hw,  const float* __restrict__ hb,
    float* __restrict__ tab)
{
    __shared__ vf4 lwt4[2048];             // 32 KB, swizzled row-major e1w
    const int lane = threadIdx.x;          // 0..63 (one wave)

    const vf4* e1w4 = (const vf4*)e1w;
    #pragma unroll
    for (int i = 0; i < 32; ++i) {
        int idx4 = i * 64 + lane;          // 0..2047
        int row  = idx4 >> 5;              // 0..63
        int ch   = idx4 & 31;              // 0..31
        lwt4[(row * 32 + (row & 31)) ^ ch] = e1w4[idx4];
    }
    __syncthreads();

    const int e = blockIdx.x;              // table entry 0..NTAB

    const float t  = -TLIM + (2.0f * TLIM) * (float)e / (float)NTAB;
    const float sv = fsigmoid(t);

    const int bidx = lane * 32 + (lane & 31);
    float a0 = e1b[lane], a1 = 0.0f, a2 = 0.0f, a3 = 0.0f;
    #pragma unroll
    for (int c = 0; c < 32; ++c) {
        vf4 w4 = lwt4[bidx ^ c];           // chunk c of row `lane`
        const int k = 4 * c;
        float h10 = fmaxf(fmaf(e0w[k + 0], sv, e0b[k + 0]), 0.0f);
        float h11 = fmaxf(fmaf(e0w[k + 1], sv, e0b[k + 1]), 0.0f);
        float h12 = fmaxf(fmaf(e0w[k + 2], sv, e0b[k + 2]), 0.0f);
        float h13 = fmaxf(fmaf(e0w[k + 3], sv, e0b[k + 3]), 0.0f);
        a0 = fmaf(w4.x, h10, a0);
        a1 = fmaf(w4.y, h11, a1);
        a2 = fmaf(w4.z, h12, a2);
        a3 = fmaf(w4.w, h13, a3);
    }
    float h2 = fmaxf((a0 + a1) + (a2 + a3), 0.0f);

    float v0 = e2w[lane] * h2;
    float v1 = e2w[64 + lane] * h2;
    #pragma unroll
    for (int off = 32; off > 0; off >>= 1) {
        v0 += __shfl_xor(v0, off);
        v1 += __shfl_xor(v1, off);
    }
    float l0 = v0 + e2b[0];
    float l1 = v1 + e2b[1];

    float y0[4], y1[4], y2[3], y3[2];
    #pragma unroll
    for (int o = 0; o < 4; ++o)
        y0[o] = ftanh(fmaf(fmw[o*2], l0, fmaf(fmw[o*2+1], l1, fmb[o])));
    #pragma unroll
    for (int o = 0; o < 4; ++o)
        y1[o] = ftanh(fmaf(c1w[o*4], y0[0], fmaf(c1w[o*4+1], y0[1],
                      fmaf(c1w[o*4+2], y0[2], fmaf(c1w[o*4+3], y0[3], c1b[o])))));
    #pragma unroll
    for (int o = 0; o < 3; ++o)
        y2[o] = ftanh(fmaf(p1w[o*4], y1[0], fmaf(p1w[o*4+1], y1[1],
                      fmaf(p1w[o*4+2], y1[2], fmaf(p1w[o*4+3], y1[3], p1b[o])))));
    #pragma unroll
    for (int o = 0; o < 2; ++o)
        y3[o] = ftanh(fmaf(c2w[o*3], y2[0], fmaf(c2w[o*3+1], y2[1],
                      fmaf(c2w[o*3+2], y2[2], c2b[o]))));
    float y4 = ftanh(fmaf(p2w[0], y3[0], fmaf(p2w[1], y3[1], p2b[0])));
    float y5 = ftanh(fmaf(c3w[0], y4, c3b[0]));
    float g0 = fmaf(hw[0], y5, hb[0]);
    float g1 = fmaf(hw[1], y5, hb[1]);
    float p0 = fsigmoid(g0 - g1);          // softmax over 2 logits

    if (lane == 0) tab[e] = p0;
}

// ---------------------------------------------------------------------------
// Kernel 2: memory-bound eval. 4 samples/thread, 1024 blocks (16 waves/CU
// for latency hiding; R9 had 8). Lane-dense dwordx4 loads / b64 stores, all
// nontemporal (streaming data, keep table+weights in cache). LDS table =
// 128 (value,delta) entries staged by threads 0..127 (clamp => k<=127).
// ---------------------------------------------------------------------------
__global__ __launch_bounds__(256) void eval_kernel(
    const vf4* __restrict__ x4,
    const float* __restrict__ convw,
    const float* __restrict__ convb,
    const float* __restrict__ tab,
    vf2* __restrict__ out2)
{
    __shared__ vf2 ltab[NTAB];
    const int tid  = threadIdx.x;
    const int base = blockIdx.x * 1024;   // 1024 samples per block

    // Issue x loads first: 4 dwordx4 in flight per lane during staging.
    vf4 xs[4];
    #pragma unroll
    for (int j = 0; j < 4; ++j)
        xs[j] = __builtin_nontemporal_load(&x4[base + j * 256 + tid]);

    // Stage table: one (value, delta) entry per thread for tid < 128.
    if (tid < NTAB) {
        float v  = tab[tid];
        float vn = tab[tid + 1];
        vf2 e; e.x = v; e.y = vn - v;
        ltab[tid] = e;
    }
    __syncthreads();

    const float scale = (float)NTAB / (2.0f * TLIM);   // 8.0f
    const float w0 = convw[0] * scale, w1 = convw[1] * scale,
                w2 = convw[2] * scale, w3 = convw[3] * scale;
    const float cb = (convb[0] + TLIM) * scale;

    #pragma unroll
    for (int j = 0; j < 4; ++j) {
        float f = fmaf(xs[j].x, w0, fmaf(xs[j].y, w1,
                  fmaf(xs[j].z, w2, fmaf(xs[j].w, w3, cb))));
        f = fminf(fmaxf(f, 0.0f), (float)NTAB - 0.001f);
        int   k = (int)f;
        float r = f - (float)k;
        vf2 vd = ltab[k];
        float p = fmaf(r, vd.y, vd.x);
        vf2 o; o.x = p; o.y = 1.0f - p;
        __builtin_nontemporal_store(o, &out2[base + j * 256 + tid]);
    }
}

extern "C" void kernel_launch(void* const* d_in, const int* in_sizes, int n_in,
                              void* d_out, int out_size, void* d_ws, size_t ws_size,
                              hipStream_t stream) {
    const float* x     = (const float*)d_in[0];
    const float* convw = (const float*)d_in[1];
    const float* convb = (const float*)d_in[2];
    const float* e0w   = (const float*)d_in[3];
    const float* e0b   = (const float*)d_in[4];
    const float* e1w   = (const float*)d_in[5];
    const float* e1b   = (const float*)d_in[6];
    const float* e2w   = (const float*)d_in[7];
    const float* e2b   = (const float*)d_in[8];
    const float* fmw   = (const float*)d_in[9];
    const float* fmb   = (const float*)d_in[10];
    const float* c1w   = (const float*)d_in[11];
    const float* c1b   = (const float*)d_in[12];
    const float* p1w   = (const float*)d_in[13];
    const float* p1b   = (const float*)d_in[14];
    const float* c2w   = (const float*)d_in[15];
    const float* c2b   = (const float*)d_in[16];
    const float* p2w   = (const float*)d_in[17];
    const float* p2b   = (const float*)d_in[18];
    const float* c3w   = (const float*)d_in[19];
    const float* c3b   = (const float*)d_in[20];
    const float* hw    = (const float*)d_in[21];
    const float* hb    = (const float*)d_in[22];

    float* tab = (float*)d_ws;                 // 129 floats

    const int B = in_sizes[0] / 4;             // 1048576 samples

    // Build LUT: one wave / one entry per block, 129 blocks (all parallel).
    build_tab_kernel<<<NTAB + 1, 64, 0, stream>>>(
        e0w, e0b, e1w, e1b, e2w, e2b, fmw, fmb, c1w, c1b,
        p1w, p1b, c2w, c2b, p2w, p2b, c3w, c3b, hw, hb, tab);

    // Evaluate: 1024 samples per block, 1024 blocks.
    int nblocks = B / 1024;                    // 1024
    eval_kernel<<<nblocks, 256, 0, stream>>>(
        (const vf4*)x, convw, convb, tab, (vf2*)d_out);
}

// Round 12
// 12.637 us; speedup vs baseline: 1.2613x; 1.0984x over previous
//
#include <hip/hip_runtime.h>
#include <math.h>

#define NTAB 128             // table intervals; table has NTAB+1 = 129 entries
#define TLIM 8.0f            // t range [-TLIM, TLIM]

// clang native vector types (ext_vector_type) — required for
// __builtin_nontemporal_load/store, which rejects HIP_vector_type structs.
typedef float vf4 __attribute__((ext_vector_type(4)));
typedef float vf2 __attribute__((ext_vector_type(2)));

// fast tanh / sigmoid via v_exp_f32 + v_rcp_f32 (rel err ~1e-5, threshold 1.5e-2)
__device__ __forceinline__ float ftanh(float x) {
    float e = __expf(2.0f * x);
    return 1.0f - 2.0f * __builtin_amdgcn_rcpf(e + 1.0f);
}
__device__ __forceinline__ float fsigmoid(float x) {
    return __builtin_amdgcn_rcpf(1.0f + __expf(-x));
}

// ---------------------------------------------------------------------------
// Kernel 1: build LUT p(t), 129 entries. ONE WAVE per block, one entry per
// block, 129 parallel blocks. NO LDS: lane j reads its own e1_w row (512 B)
// directly from global as 32 independent dwordx4 — all 129 blocks hit the
// same 32 KB, L2-resident after first touch; 4 chunks per 64B line via L1.
// Removes the R9 LDS write+barrier+read round-trip (~0.3us of critical path).
// ---------------------------------------------------------------------------
__global__ __launch_bounds__(64) void build_tab_kernel(
    const float* __restrict__ e0w, const float* __restrict__ e0b,
    const float* __restrict__ e1w, const float* __restrict__ e1b,
    const float* __restrict__ e2w, const float* __restrict__ e2b,
    const float* __restrict__ fmw, const float* __restrict__ fmb,
    const float* __restrict__ c1w, const float* __restrict__ c1b,
    const float* __restrict__ p1w, const float* __restrict__ p1b,
    const float* __restrict__ c2w, const float* __restrict__ c2b,
    const float* __restrict__ p2w, const float* __restrict__ p2b,
    const float* __restrict__ c3w, const float* __restrict__ c3b,
    const float* __restrict__ hw,  const float* __restrict__ hb,
    float* __restrict__ tab)
{
    const int lane = threadIdx.x;          // 0..63 (one wave)
    const int e = blockIdx.x;              // table entry 0..NTAB

    const float t  = -TLIM + (2.0f * TLIM) * (float)e / (float)NTAB;
    const float sv = fsigmoid(t);

    // h2[lane] = relu( sum_k e1w[lane,k] * relu(e0w[k]*sv + e0b[k]) + e1b[lane] )
    const vf4* row = (const vf4*)(e1w + lane * 128);   // lane's own row
    float a0 = e1b[lane], a1 = 0.0f, a2 = 0.0f, a3 = 0.0f;
    #pragma unroll
    for (int c = 0; c < 32; ++c) {
        vf4 w4 = row[c];
        const int k = 4 * c;
        float h10 = fmaxf(fmaf(e0w[k + 0], sv, e0b[k + 0]), 0.0f);
        float h11 = fmaxf(fmaf(e0w[k + 1], sv, e0b[k + 1]), 0.0f);
        float h12 = fmaxf(fmaf(e0w[k + 2], sv, e0b[k + 2]), 0.0f);
        float h13 = fmaxf(fmaf(e0w[k + 3], sv, e0b[k + 3]), 0.0f);
        a0 = fmaf(w4.x, h10, a0);
        a1 = fmaf(w4.y, h11, a1);
        a2 = fmaf(w4.z, h12, a2);
        a3 = fmaf(w4.w, h13, a3);
    }
    float h2 = fmaxf((a0 + a1) + (a2 + a3), 0.0f);

    // latent = e2_w (2x64) @ h2 + e2_b : butterfly reduction
    float v0 = e2w[lane] * h2;
    float v1 = e2w[64 + lane] * h2;
    #pragma unroll
    for (int off = 32; off > 0; off >>= 1) {
        v0 += __shfl_xor(v0, off);
        v1 += __shfl_xor(v1, off);
    }
    float l0 = v0 + e2b[0];
    float l1 = v1 + e2b[1];

    // QCNN tanh chain (tiny; redundant per lane; fast-exp tanh)
    float y0[4], y1[4], y2[3], y3[2];
    #pragma unroll
    for (int o = 0; o < 4; ++o)
        y0[o] = ftanh(fmaf(fmw[o*2], l0, fmaf(fmw[o*2+1], l1, fmb[o])));
    #pragma unroll
    for (int o = 0; o < 4; ++o)
        y1[o] = ftanh(fmaf(c1w[o*4], y0[0], fmaf(c1w[o*4+1], y0[1],
                      fmaf(c1w[o*4+2], y0[2], fmaf(c1w[o*4+3], y0[3], c1b[o])))));
    #pragma unroll
    for (int o = 0; o < 3; ++o)
        y2[o] = ftanh(fmaf(p1w[o*4], y1[0], fmaf(p1w[o*4+1], y1[1],
                      fmaf(p1w[o*4+2], y1[2], fmaf(p1w[o*4+3], y1[3], p1b[o])))));
    #pragma unroll
    for (int o = 0; o < 2; ++o)
        y3[o] = ftanh(fmaf(c2w[o*3], y2[0], fmaf(c2w[o*3+1], y2[1],
                      fmaf(c2w[o*3+2], y2[2], c2b[o]))));
    float y4 = ftanh(fmaf(p2w[0], y3[0], fmaf(p2w[1], y3[1], p2b[0])));
    float y5 = ftanh(fmaf(c3w[0], y4, c3b[0]));
    float g0 = fmaf(hw[0], y5, hb[0]);
    float g1 = fmaf(hw[1], y5, hb[1]);
    float p0 = fsigmoid(g0 - g1);          // softmax over 2 logits

    if (lane == 0) tab[e] = p0;
}

// ---------------------------------------------------------------------------
// Kernel 2 (R11-proven, unchanged): memory-bound eval. 4 samples/thread,
// 1024 blocks, lane-dense nontemporal dwordx4 loads / b64 stores. LDS table
// = 128 (value,delta) entries staged by threads 0..127 (clamp => k<=127).
// ---------------------------------------------------------------------------
__global__ __launch_bounds__(256) void eval_kernel(
    const vf4* __restrict__ x4,
    const float* __restrict__ convw,
    const float* __restrict__ convb,
    const float* __restrict__ tab,
    vf2* __restrict__ out2)
{
    __shared__ vf2 ltab[NTAB];
    const int tid  = threadIdx.x;
    const int base = blockIdx.x * 1024;   // 1024 samples per block

    // Issue x loads first: 4 dwordx4 in flight per lane during staging.
    vf4 xs[4];
    #pragma unroll
    for (int j = 0; j < 4; ++j)
        xs[j] = __builtin_nontemporal_load(&x4[base + j * 256 + tid]);

    // Stage table: one (value, delta) entry per thread for tid < 128.
    if (tid < NTAB) {
        float v  = tab[tid];
        float vn = tab[tid + 1];
        vf2 e; e.x = v; e.y = vn - v;
        ltab[tid] = e;
    }
    __syncthreads();

    const float scale = (float)NTAB / (2.0f * TLIM);   // 8.0f
    const float w0 = convw[0] * scale, w1 = convw[1] * scale,
                w2 = convw[2] * scale, w3 = convw[3] * scale;
    const float cb = (convb[0] + TLIM) * scale;

    #pragma unroll
    for (int j = 0; j < 4; ++j) {
        float f = fmaf(xs[j].x, w0, fmaf(xs[j].y, w1,
                  fmaf(xs[j].z, w2, fmaf(xs[j].w, w3, cb))));
        f = fminf(fmaxf(f, 0.0f), (float)NTAB - 0.001f);
        int   k = (int)f;
        float r = f - (float)k;
        vf2 vd = ltab[k];
        float p = fmaf(r, vd.y, vd.x);
        vf2 o; o.x = p; o.y = 1.0f - p;
        __builtin_nontemporal_store(o, &out2[base + j * 256 + tid]);
    }
}

extern "C" void kernel_launch(void* const* d_in, const int* in_sizes, int n_in,
                              void* d_out, int out_size, void* d_ws, size_t ws_size,
                              hipStream_t stream) {
    const float* x     = (const float*)d_in[0];
    const float* convw = (const float*)d_in[1];
    const float* convb = (const float*)d_in[2];
    const float* e0w   = (const float*)d_in[3];
    const float* e0b   = (const float*)d_in[4];
    const float* e1w   = (const float*)d_in[5];
    const float* e1b   = (const float*)d_in[6];
    const float* e2w   = (const float*)d_in[7];
    const float* e2b   = (const float*)d_in[8];
    const float* fmw   = (const float*)d_in[9];
    const float* fmb   = (const float*)d_in[10];
    const float* c1w   = (const float*)d_in[11];
    const float* c1b   = (const float*)d_in[12];
    const float* p1w   = (const float*)d_in[13];
    const float* p1b   = (const float*)d_in[14];
    const float* c2w   = (const float*)d_in[15];
    const float* c2b   = (const float*)d_in[16];
    const float* p2w   = (const float*)d_in[17];
    const float* p2b   = (const float*)d_in[18];
    const float* c3w   = (const float*)d_in[19];
    const float* c3b   = (const float*)d_in[20];
    const float* hw    = (const float*)d_in[21];
    const float* hb    = (const float*)d_in[22];

    float* tab = (float*)d_ws;                 // 129 floats

    const int B = in_sizes[0] / 4;             // 1048576 samples

    // Build LUT: one wave / one entry per block, 129 blocks (all parallel).
    build_tab_kernel<<<NTAB + 1, 64, 0, stream>>>(
        e0w, e0b, e1w, e1b, e2w, e2b, fmw, fmb, c1w, c1b,
        p1w, p1b, c2w, c2b, p2w, p2b, c3w, c3b, hw, hb, tab);

    // Evaluate: 1024 samples per block, 1024 blocks.
    int nblocks = B / 1024;                    // 1024
    eval_kernel<<<nblocks, 256, 0, stream>>>(
        (const vf4*)x, convw, convb, tab, (vf2*)d_out);
}